// Round 12
// baseline (1291.860 us; speedup 1.0000x reference)
//
#include <hip/hip_runtime.h>

// Problem constants (fixed instance): all float tensors are float32 on device.
#define NPL   16384        // nodes per level
#define DIM   64
#define CPN   8            // children per node
#define EPL   (NPL * CPN)  // edges per level block = 131072
#define NLEV  8

#define TPB     512        // 8 waves/block (TPB=1024 pins a 64-VGPR cap, R3-R5)
#define WPB     (TPB / 64)
#define CBLOCKS 256        // 1 block/CU (2/CU was 2.25x worse, R7)
#define NPB     (NPL / CBLOCKS)   // 64 nodes per block per level
#define NPW     (NPB / WPB)       // 8 nodes per wave per level

#define SPIN_CAP (1 << 18) // ~262k poll iters (>=1000x any legit wait). R9
                           // lesson: hangs kill containers silently; capped
                           // spins produce passed:false (diagnosable).

// ---- R12 design: BARRIER-FREE DATAFLOW ------------------------------------
// flags[row>>3] (16384 ints, 64 KiB at ws[0..64KiB)): one ready-flag per
// writer-wave per level (each wave owns 8 consecutive rows/level). Writer
// publishes with a RELEASE store (drains its vmcnt -> same ordering the
// proven gridbar got from __syncthreads). Readers poll with relaxed
// agent-scope loads (R10 proved these observe cross-XCD updates), 64 child
// flags in parallel (one load/lane + ballot). No grid barriers at all ->
// no global-max skew per level; waves run fully asynchronously.
// XR is REGISTER-RESIDENT per level (xrr[8]): the R1/R2 spills came from
// holding 56 values across the kernel; interleaving XR-compute with each
// level's gather phase shrinks the lifetime to 8 floats. Removes the
// 29.3 MB XR write + 29.3 MB read entirely.

__device__ __forceinline__ void co_st(float* p, float v) {
    __hip_atomic_store(p, v, __ATOMIC_RELAXED, __HIP_MEMORY_SCOPE_AGENT);
}

__device__ __forceinline__ void load_wrow(float* dst, const float* W, int row) {
    const float4* p = (const float4*)(W + row * DIM);
    #pragma unroll
    for (int q = 0; q < DIM / 4; ++q) {
        float4 v = p[q];
        dst[4*q+0] = v.x; dst[4*q+1] = v.y;
        dst[4*q+2] = v.z; dst[4*q+3] = v.w;
    }
}

// tanh via hardware exp + rcp. |err| ~1e-6, threshold is 5.9e-2.
__device__ __forceinline__ float fast_tanh(float z) {
    z = fminf(15.f, fmaxf(-15.f, z));
    float e = __expf(-2.f * z);
    return (1.f - e) * __builtin_amdgcn_rcpf(1.f + e);
}

// ---------------- Fused dataflow kernel (1 dispatch, no barriers) ----------
// launch_bounds(512,1): VGPR cap 256. Live set ~200 (wr 64 + wl 64 + ring 32
// + xrr 8 + misc) -- must NOT hit a 128 cap ((512,2) would spill, R1 lesson).
__global__ __launch_bounds__(TPB, 1) void dag_fused(
    const float* __restrict__ x, const int* __restrict__ src,
    const float* __restrict__ Wl, const float* __restrict__ bl,
    const float* __restrict__ Wr, float* __restrict__ out,
    float* __restrict__ ws)
{
    __shared__ __align__(16) float sbuf[WPB][256];

    const int lane = threadIdx.x & 63;
    const int w    = threadIdx.x >> 6;
    float*    sX   = sbuf[w];            // per-wave scratch (in-order DS)
    int*      flags = (int*)ws;          // 64 KiB ready flags

    const int base = blockIdx.x * NPB + w * NPW;   // this wave's 8 nodes/level
    const int sub  = lane >> 4;                    // row within 4-row group
    const int col4 = (lane & 15) * 4;              // float4 offset in dim

    // Preload ALL levels' child indices (one coalesced load each).
    int vidx[NLEV - 1];
    #pragma unroll
    for (int L = 1; L < NLEV; ++L)
        vidx[L - 1] = src[(long)(L - 1) * EPL + base * CPN + lane];

    float wr[DIM]; load_wrow(wr, Wr, lane);
    float wl[DIM]; load_wrow(wl, Wl, lane);
    const float bias = bl[lane];

    // ---- Level 0: out[base..base+8) = x @ Wr^T (final values), publish. ---
    float4 qa = *(const float4*)&x[(long)(base + sub) * DIM + col4];
    float4 qb = *(const float4*)&x[(long)(base + 4 + sub) * DIM + col4];

    #pragma unroll
    for (int grp = 0; grp < 2; ++grp) {
        *(float4*)&sX[sub * DIM + col4] = (grp == 0) ? qa : qb;
        #pragma unroll
        for (int rr = 0; rr < 4; ++rr) {
            float a0 = 0.f, a1 = 0.f, a2 = 0.f, a3 = 0.f;
            const float4* A = (const float4*)&sX[rr * DIM];    // broadcast
            #pragma unroll
            for (int k = 0; k < DIM / 4; ++k) {
                float4 av = A[k];
                a0 += av.x * wr[4*k+0];
                a1 += av.y * wr[4*k+1];
                a2 += av.z * wr[4*k+2];
                a3 += av.w * wr[4*k+3];
            }
            co_st(&out[(long)(base + grp * 4 + rr) * DIM + lane],
                  (a0 + a1) + (a2 + a3));
        }
    }

    // Prefetch level-1 x rows (in flight across the flag publish).
    qa = *(const float4*)&x[(long)(NPL + base + sub) * DIM + col4];
    qb = *(const float4*)&x[(long)(NPL + base + 4 + sub) * DIM + col4];

    // Publish L0: RELEASE drains this wave's vmcnt (all 8 rows at the
    // coherent point) before the flag becomes visible.
    if (lane == 0)
        __hip_atomic_store(flags + (base >> 3), 1, __ATOMIC_RELEASE,
                           __HIP_MEMORY_SCOPE_AGENT);

    // ---- Levels 1..7: xr in registers, poll children, gather, compute. ----
    #pragma unroll
    for (int L = 1; L < NLEV; ++L) {
        const long gbase = (long)L * NPL;

        // xr for my 8 rows of THIS level (same lane computes the element it
        // later consumes: r = x_row . Wr[lane,:]).
        float xrr[8];
        #pragma unroll
        for (int grp = 0; grp < 2; ++grp) {
            *(float4*)&sX[sub * DIM + col4] = (grp == 0) ? qa : qb;
            #pragma unroll
            for (int rr = 0; rr < 4; ++rr) {
                float a0 = 0.f, a1 = 0.f, a2 = 0.f, a3 = 0.f;
                const float4* A = (const float4*)&sX[rr * DIM];
                #pragma unroll
                for (int k = 0; k < DIM / 4; ++k) {
                    float4 av = A[k];
                    a0 += av.x * wr[4*k+0];
                    a1 += av.y * wr[4*k+1];
                    a2 += av.z * wr[4*k+2];
                    a3 += av.w * wr[4*k+3];
                }
                xrr[grp * 4 + rr] = (a0 + a1) + (a2 + a3);
            }
        }

        // Prefetch next level's x rows (latency hidden under poll + ring).
        if (L + 1 < NLEV) {
            qa = *(const float4*)&x[((L + 1) * (long)NPL + base + sub) * DIM + col4];
            qb = *(const float4*)&x[((L + 1) * (long)NPL + base + 4 + sub) * DIM + col4];
        }

        // Poll the 64 child-wave flags (one per lane) until all ready.
        {
            const int fid = vidx[L - 1] >> 3;   // global row>>3 = flag cell
            for (int it = 0; it < SPIN_CAP; ++it) {
                int f = __hip_atomic_load(flags + fid, __ATOMIC_RELAXED,
                                          __HIP_MEMORY_SCOPE_AGENT);
                if (__ballot(f != 0) == ~0ull) break;
                __builtin_amdgcn_s_sleep(1);
            }
        }

        // Gather ring: 4 slots, prefetch distance 3 (proven structure).
        float g[4][CPN];
        #define ISSUE(c, s)                                                   \
            {                                                                 \
                _Pragma("unroll")                                             \
                for (int j = 0; j < CPN; ++j) {                               \
                    int si = __builtin_amdgcn_readlane(vidx[L - 1],           \
                                                       (c) * CPN + j);        \
                    g[s][j] = out[(long)si * DIM + lane];                     \
                }                                                             \
            }

        ISSUE(0, 0);
        ISSUE(1, 1);
        ISSUE(2, 2);

        #pragma unroll
        for (int c = 0; c < NPW; ++c) {
            const int slot = c & 3;
            if (c + 3 < NPW) ISSUE(c + 3, (c + 3) & 3);   // != slot, always

            float s0 = g[slot][0] + g[slot][1];
            float s1 = g[slot][2] + g[slot][3];
            float s2 = g[slot][4] + g[slot][5];
            float s3 = g[slot][6] + g[slot][7];
            float agg = (s0 + s1) + (s2 + s3);
            sX[lane] = agg;                        // per-wave, in-order DS

            float a0 = 0.f, a1 = 0.f, a2 = 0.f, a3 = bias + xrr[c];
            const float4* B = (const float4*)sX;   // broadcast: conflict-free
            #pragma unroll
            for (int k = 0; k < DIM / 4; ++k) {
                float4 bv = B[k];
                a0 += bv.x * wl[4*k+0];
                a1 += bv.y * wl[4*k+1];
                a2 += bv.z * wl[4*k+2];
                a3 += bv.w * wl[4*k+3];
            }
            float r = fast_tanh((a0 + a1) + (a2 + a3));
            co_st(&out[(gbase + base + c) * DIM + lane], r);
        }
        #undef ISSUE

        // Publish this level's 8 rows (RELEASE drains the co_st stores).
        if (L + 1 < NLEV && lane == 0)
            __hip_atomic_store(flags + (int)((gbase + base) >> 3), 1,
                               __ATOMIC_RELEASE, __HIP_MEMORY_SCOPE_AGENT);
    }
}

// ---------------- Fallback: normal launches (kernel-boundary coherence) ----
// No flags, XR in global at ws + 16384 floats (proven R0-style structure).
__global__ __launch_bounds__(TPB) void dag_phaseA_k(
    const float* __restrict__ x, const float* __restrict__ Wr,
    float* __restrict__ out, float* __restrict__ ws)
{
    __shared__ __align__(16) float sbuf[WPB][256];
    const int lane = threadIdx.x & 63;
    const int w    = threadIdx.x >> 6;
    float* sX = sbuf[w];
    float* XR = ws + 16384;

    const int base = blockIdx.x * NPB + w * NPW;
    const int sub  = lane >> 4;
    const int col4 = (lane & 15) * 4;

    float wr[DIM]; load_wrow(wr, Wr, lane);

    for (int L = 0; L < NLEV; ++L) {
        #pragma unroll
        for (int grp = 0; grp < 2; ++grp) {
            float4 q = *(const float4*)
                &x[((long)L * NPL + base + grp * 4 + sub) * DIM + col4];
            *(float4*)&sX[sub * DIM + col4] = q;
            #pragma unroll
            for (int rr = 0; rr < 4; ++rr) {
                float a0 = 0.f, a1 = 0.f, a2 = 0.f, a3 = 0.f;
                const float4* A = (const float4*)&sX[rr * DIM];
                #pragma unroll
                for (int k = 0; k < DIM / 4; ++k) {
                    float4 av = A[k];
                    a0 += av.x * wr[4*k+0];
                    a1 += av.y * wr[4*k+1];
                    a2 += av.z * wr[4*k+2];
                    a3 += av.w * wr[4*k+3];
                }
                float r = (a0 + a1) + (a2 + a3);
                long gg = (long)L * NPL + base + grp * 4 + rr;
                if (L == 0) out[gg * DIM + lane] = r;
                else        XR[gg * DIM + lane] = r;
            }
        }
    }
}

__global__ __launch_bounds__(TPB) void dag_phaseB_k(
    const int* __restrict__ src, const float* __restrict__ Wl,
    const float* __restrict__ bl, float* __restrict__ out,
    float* __restrict__ ws, int L)
{
    __shared__ __align__(16) float sbuf[WPB][256];
    const int lane = threadIdx.x & 63;
    const int w    = threadIdx.x >> 6;
    float* sX = sbuf[w];
    float* XR = ws + 16384;

    const int  base  = blockIdx.x * NPB + w * NPW;
    const long gbase = (long)L * NPL;
    int vidx = src[(long)(L - 1) * EPL + base * CPN + lane];

    float wl[DIM]; load_wrow(wl, Wl, lane);
    const float bias = bl[lane];

    float g[4][CPN];
    float xr[4];

    #define ISSUE(c, s)                                                       \
        {                                                                     \
            _Pragma("unroll")                                                 \
            for (int j = 0; j < CPN; ++j) {                                   \
                int si = __builtin_amdgcn_readlane(vidx, (c) * CPN + j);      \
                g[s][j] = out[(long)si * DIM + lane];                         \
            }                                                                 \
            xr[s] = XR[(gbase + base + (c)) * DIM + lane];                    \
        }

    ISSUE(0, 0);
    ISSUE(1, 1);
    ISSUE(2, 2);

    #pragma unroll
    for (int c = 0; c < NPW; ++c) {
        const int slot = c & 3;
        if (c + 3 < NPW) ISSUE(c + 3, (c + 3) & 3);

        float s0 = g[slot][0] + g[slot][1];
        float s1 = g[slot][2] + g[slot][3];
        float s2 = g[slot][4] + g[slot][5];
        float s3 = g[slot][6] + g[slot][7];
        float agg = (s0 + s1) + (s2 + s3);
        sX[lane] = agg;

        float a0 = 0.f, a1 = 0.f, a2 = 0.f, a3 = bias + xr[slot];
        const float4* B = (const float4*)sX;
        #pragma unroll
        for (int k = 0; k < DIM / 4; ++k) {
            float4 bv = B[k];
            a0 += bv.x * wl[4*k+0];
            a1 += bv.y * wl[4*k+1];
            a2 += bv.z * wl[4*k+2];
            a3 += bv.w * wl[4*k+3];
        }
        out[(gbase + base + c) * DIM + lane] =
            fast_tanh((a0 + a1) + (a2 + a3));
    }
    #undef ISSUE
}

extern "C" void kernel_launch(void* const* d_in, const int* in_sizes, int n_in,
                              void* d_out, int out_size, void* d_ws, size_t ws_size,
                              hipStream_t stream) {
    const float* x  = (const float*)d_in[0];   // [131072,64] f32
    const int*   ei = (const int*)d_in[1];     // [2, 917504] int32
    const float* Wl = (const float*)d_in[2];   // [64,64] f32
    const float* bl = (const float*)d_in[3];   // [64]    f32
    const float* Wr = (const float*)d_in[4];   // [64,64] f32
    float* out = (float*)d_out;                // [131072,64] f32
    float* ws  = (float*)d_ws;                 // [0..64KiB)=flags; +16384f=XR(fallback)

    const int* src = ei;                       // first E entries = src row

    // Zero the ready-flag region inside the captured work (d_ws is
    // re-poisoned 0xAA before every timed launch).
    hipMemsetAsync(ws, 0, 65536, stream);

    void* args[] = {(void*)&x, (void*)&src, (void*)&Wl, (void*)&bl,
                    (void*)&Wr, (void*)&out, (void*)&ws};
    hipError_t e = hipLaunchCooperativeKernel((const void*)dag_fused,
                                              dim3(CBLOCKS), dim3(TPB),
                                              args, 0, stream);
    if (e != hipSuccess) {
        (void)hipGetLastError();               // clear sticky error
        hipLaunchKernelGGL(dag_phaseA_k, dim3(CBLOCKS), dim3(TPB), 0, stream,
                           x, Wr, out, ws);
        for (int L = 1; L < NLEV; ++L) {
            hipLaunchKernelGGL(dag_phaseB_k, dim3(CBLOCKS), dim3(TPB), 0, stream,
                               src, Wl, bl, out, ws, L);
        }
    }
}